// Round 5
// baseline (160.344 us; speedup 1.0000x reference)
//
#include <hip/hip_runtime.h>

#define Bn 64
#define Dn 128
#define Ln 512

typedef __attribute__((ext_vector_type(8))) short short8;
typedef __attribute__((ext_vector_type(4))) float f32x4;

// truncating bf16 split: x ~= hi + lo
__device__ __forceinline__ void split8(const float* xs, short8& hi, short8& lo) {
#pragma unroll
  for (int j = 0; j < 8; ++j) {
    unsigned int u = __float_as_uint(xs[j]);
    float l = xs[j] - __uint_as_float(u & 0xFFFF0000u);
    hi[j] = (short)(u >> 16);
    lo[j] = (short)(__float_as_uint(l) >> 16);
  }
}

// ---- kz: Z[bh][m][d] = sum_e X2[m,b,e] WU[h,d,e]; writes fragment-ordered
// bf16 hi/lo images: unit(bh, cg=d>>4, ks, comp) of 1KB; lane ln holds
// Z[cg*16+(ln&15)][ks*32+(ln>>4)*8 .. +8]. grid 1024: blk = b*16+mt*4+h.
__global__ __launch_bounds__(256, 2) void kz(const float* __restrict__ X2,
                                             const float* __restrict__ WU,
                                             unsigned short* __restrict__ zimg) {
  __shared__ __align__(16) float zt[128 * 132];
  int orig = blockIdx.x;
  int blk = (orig & 7) * 128 + (orig >> 3);  // XCD swizzle
  int h = blk & 3, mt = (blk >> 2) & 3, b = blk >> 4;
  int t = threadIdx.x, ln = t & 63, wv = t >> 6;
  int R0 = (wv >> 1) * 64, C0 = (wv & 1) * 64;
  int eo = (ln >> 4) * 8;

  f32x4 acc[4][4];
  const f32x4 fz = {0.f, 0.f, 0.f, 0.f};
#pragma unroll
  for (int i = 0; i < 4; ++i)
#pragma unroll
    for (int j = 0; j < 4; ++j) acc[i][j] = fz;

#pragma unroll
  for (int ks = 0; ks < 4; ++ks) {
    short8 ahf[4], alf[4], bhf[4], blf[4];
#pragma unroll
    for (int mr = 0; mr < 4; ++mr) {
      int m = mt * 128 + R0 + mr * 16 + (ln & 15);
      const float* src = X2 + ((size_t)m * Bn + b) * Dn + ks * 32 + eo;
      float xs[8];
      *(float4*)xs = *(const float4*)src;
      *(float4*)(xs + 4) = *(const float4*)(src + 4);
      split8(xs, ahf[mr], alf[mr]);
    }
#pragma unroll
    for (int nr = 0; nr < 4; ++nr) {
      int d = C0 + nr * 16 + (ln & 15);
      const float* src = WU + ((size_t)(h * Dn + d)) * Dn + ks * 32 + eo;
      float xs[8];
      *(float4*)xs = *(const float4*)src;
      *(float4*)(xs + 4) = *(const float4*)(src + 4);
      split8(xs, bhf[nr], blf[nr]);
    }
#pragma unroll
    for (int mr = 0; mr < 4; ++mr)
#pragma unroll
      for (int nr = 0; nr < 4; ++nr) {
        acc[mr][nr] = __builtin_amdgcn_mfma_f32_16x16x32_bf16(ahf[mr], bhf[nr], acc[mr][nr], 0, 0, 0);
        acc[mr][nr] = __builtin_amdgcn_mfma_f32_16x16x32_bf16(ahf[mr], blf[nr], acc[mr][nr], 0, 0, 0);
        acc[mr][nr] = __builtin_amdgcn_mfma_f32_16x16x32_bf16(alf[mr], bhf[nr], acc[mr][nr], 0, 0, 0);
      }
  }
  // transpose via LDS: frag layout -> row-major rows of Z
#pragma unroll
  for (int mr = 0; mr < 4; ++mr) {
    int rb = R0 + mr * 16 + (ln >> 4) * 4;
#pragma unroll
    for (int nr = 0; nr < 4; ++nr) {
      int d = C0 + nr * 16 + (ln & 15);
#pragma unroll
      for (int j = 0; j < 4; ++j) zt[(rb + j) * 132 + d] = acc[mr][nr][j];
    }
  }
  __syncthreads();
  int bh = b * 4 + h;
#pragma unroll
  for (int p = 0; p < 8; ++p) {
    int u = p * 4 + (t >> 6);  // 0..31 : (mgrp_local = u>>2, ks = u&3)
    int r = (u >> 2) * 16 + (ln & 15);
    int d = (u & 3) * 32 + (ln >> 4) * 8;
    float xs[8];
    *(float4*)xs = *(const float4*)(zt + r * 132 + d);
    *(float4*)(xs + 4) = *(const float4*)(zt + r * 132 + d + 4);
    short8 hi, lo;
    split8(xs, hi, lo);
    size_t ub = ((((size_t)bh * 32 + mt * 8 + (u >> 2)) * 4 + (u & 3)) * 2) * 512 + (size_t)ln * 8;
    *(short8*)(zimg + ub) = hi;
    *(short8*)(zimg + ub + 512) = lo;
  }
}

// ---- k1: masked row/col maxes of S = X1 . Z^T. grid 1024: b*16+h*4+lt.
// Barrier-free main loop; B streamed global->regs with ring-4 prefetch.
__global__ __launch_bounds__(256, 2) void k1(const float* __restrict__ X1,
                                             const unsigned short* __restrict__ zimg,
                                             const int* __restrict__ raw1,
                                             const int* __restrict__ raw2,
                                             float* __restrict__ s1pp,
                                             float* __restrict__ s2pp) {
  __shared__ float m1f[128];
  __shared__ float m2f[512];
  __shared__ float cmbuf[2][512];  // [rg][col] colmax partials

  int orig = blockIdx.x;
  int blk = (orig & 7) * 128 + (orig >> 3);
  int lt = blk & 3, h = (blk >> 2) & 3, b = blk >> 4;
  int bh = b * 4 + h;
  int t = threadIdx.x, ln = t & 63, wv = t >> 6;
  int rg = wv >> 1, cb = wv & 1;
  int R0 = rg * 64;

  for (int i = t; i < 512; i += 256) m2f[i] = (raw2[(size_t)i * Bn + b] == 0) ? 1.0e4f : 0.0f;
  if (t < 128) m1f[t] = (raw1[(size_t)(lt * 128 + t) * Bn + b] == 0) ? 1.0e4f : 0.0f;

  // B-stream base for this wave's 256-col half
  const unsigned short* __restrict__ zb =
      zimg + ((size_t)bh * 32 + cb * 16) * 4096 + (size_t)ln * 8;

  short8 rb0[2], rb1[2], rb2[2], rb3[2];  // ring of 4 slots (hi,lo)
#define LOADG(SLOT, CGI_, KS_)                                         \
  {                                                                    \
    const unsigned short* p = zb + (CGI_)*4096 + (KS_)*1024;           \
    SLOT[0] = *(const short8*)p;                                       \
    SLOT[1] = *(const short8*)(p + 512);                               \
  }
  LOADG(rb0, 0, 0);
  LOADG(rb1, 0, 1);

  // A resident: rows lt*128 + R0 + mr*16 + (ln&15), k = ks*32 + (ln>>4)*8
  short8 ahf[4][4], alf[4][4];
  {
    int eo = (ln >> 4) * 8;
#pragma unroll
    for (int mr = 0; mr < 4; ++mr) {
      const float* rsrc =
          X1 + ((size_t)(lt * 128 + R0 + mr * 16 + (ln & 15)) * Bn + b) * Dn + eo;
#pragma unroll
      for (int ks = 0; ks < 4; ++ks) {
        float xs[8];
        *(float4*)xs = *(const float4*)(rsrc + ks * 32);
        *(float4*)(xs + 4) = *(const float4*)(rsrc + ks * 32 + 4);
        split8(xs, ahf[mr][ks], alf[mr][ks]);
      }
    }
  }
  __syncthreads();  // masks ready

  float msub1[4][4];
#pragma unroll
  for (int mr = 0; mr < 4; ++mr)
#pragma unroll
    for (int j = 0; j < 4; ++j) msub1[mr][j] = m1f[R0 + mr * 16 + (ln >> 4) * 4 + j];

  float rmrun[4][4];
#pragma unroll
  for (int i = 0; i < 4; ++i)
#pragma unroll
    for (int j = 0; j < 4; ++j) rmrun[i][j] = -3.0e38f;

  const f32x4 fz = {0.f, 0.f, 0.f, 0.f};
  for (int cgi = 0; cgi < 16; ++cgi) {  // 16 cols per subphase
    float ms2 = m2f[cb * 256 + cgi * 16 + (ln & 15)];  // issued early, used late
    f32x4 acc[4];
#pragma unroll
    for (int i = 0; i < 4; ++i) acc[i] = fz;

#pragma unroll
    for (int ks = 0; ks < 4; ++ks) {
      // prefetch subphase g+2 (g = cgi*4+ks) into slot (ks+2)&3
      if (ks < 2 || cgi < 15) {
        int cgi2 = (ks < 2) ? cgi : cgi + 1;
        if ((ks + 2) % 4 == 0) LOADG(rb0, cgi2, (ks + 2) & 3)
        else if ((ks + 2) % 4 == 1) LOADG(rb1, cgi2, (ks + 2) & 3)
        else if ((ks + 2) % 4 == 2) LOADG(rb2, cgi2, (ks + 2) & 3)
        else LOADG(rb3, cgi2, (ks + 2) & 3)
      }
      short8 bh_, bl_;
      if (ks == 0) { bh_ = rb0[0]; bl_ = rb0[1]; }
      else if (ks == 1) { bh_ = rb1[0]; bl_ = rb1[1]; }
      else if (ks == 2) { bh_ = rb2[0]; bl_ = rb2[1]; }
      else { bh_ = rb3[0]; bl_ = rb3[1]; }
#pragma unroll
      for (int mr = 0; mr < 4; ++mr) {
        acc[mr] = __builtin_amdgcn_mfma_f32_16x16x32_bf16(ahf[mr][ks], bh_, acc[mr], 0, 0, 0);
        acc[mr] = __builtin_amdgcn_mfma_f32_16x16x32_bf16(ahf[mr][ks], bl_, acc[mr], 0, 0, 0);
        acc[mr] = __builtin_amdgcn_mfma_f32_16x16x32_bf16(alf[mr][ks], bh_, acc[mr], 0, 0, 0);
      }
    }

    // rowmax partials (mask2 per-col), no cross-lane here
#pragma unroll
    for (int mr = 0; mr < 4; ++mr)
#pragma unroll
      for (int j = 0; j < 4; ++j)
        rmrun[mr][j] = fmaxf(rmrun[mr][j], acc[mr][j] - ms2);

    // colmax over this wave's 64 rows (mask1)
    float v = -3.0e38f;
#pragma unroll
    for (int mr = 0; mr < 4; ++mr)
#pragma unroll
      for (int j = 0; j < 4; ++j) v = fmaxf(v, acc[mr][j] - msub1[mr][j]);
    v = fmaxf(v, __shfl_xor(v, 16));
    v = fmaxf(v, __shfl_xor(v, 32));
    if (ln < 16) cmbuf[rg][cb * 256 + cgi * 16 + ln] = v;
  }
#undef LOADG

  // epilogue: rowmax cross-lane + writes
#pragma unroll
  for (int off = 1; off < 16; off <<= 1)
#pragma unroll
    for (int mr = 0; mr < 4; ++mr)
#pragma unroll
      for (int j = 0; j < 4; ++j)
        rmrun[mr][j] = fmaxf(rmrun[mr][j], __shfl_xor(rmrun[mr][j], off));
  if ((ln & 15) == 0) {
    float* dst = s1pp + (((size_t)bh * 4 + lt) * 2 + cb) * 128;
#pragma unroll
    for (int mr = 0; mr < 4; ++mr)
#pragma unroll
      for (int j = 0; j < 4; ++j) dst[R0 + mr * 16 + (ln >> 4) * 4 + j] = rmrun[mr][j];
  }
  __syncthreads();
  for (int i = t; i < 1024; i += 256) {
    int rgi = i >> 9, col = i & 511;
    s2pp[(((size_t)bh * 4 + lt) * 2 + rgi) * 512 + col] = cmbuf[rgi][col];
  }
}

// ---- k2: per (side,b): 4 heads; wave h = tanh+softmax; joint readout ----
__global__ __launch_bounds__(256) void k2(const float* __restrict__ s1pp,
                                          const float* __restrict__ s2pp,
                                          const float* __restrict__ X1,
                                          const float* __restrict__ X2,
                                          float* __restrict__ out,
                                          float* __restrict__ rws) {
  __shared__ float aL[4][512];
  __shared__ f32x4 redv[4][8][32];
  int side = blockIdx.x >> 6, b = blockIdx.x & 63;
  int t = threadIdx.x, ln = t & 63, h = t >> 6;
  int bh = b * 4 + h;
  int base = ln * 8;

  float vals[8];
  if (side == 0) {
    int lt = base >> 7, r = base & 127;
    const float* p0 = s1pp + (((size_t)bh * 4 + lt) * 2) * 128 + r;
#pragma unroll
    for (int q = 0; q < 8; q += 4) {
      float4 va = *(const float4*)(p0 + q);
      float4 vb = *(const float4*)(p0 + 128 + q);
      vals[q + 0] = fmaxf(va.x, vb.x);
      vals[q + 1] = fmaxf(va.y, vb.y);
      vals[q + 2] = fmaxf(va.z, vb.z);
      vals[q + 3] = fmaxf(va.w, vb.w);
    }
  } else {
#pragma unroll
    for (int q = 0; q < 8; ++q) vals[q] = -3.0e38f;
#pragma unroll
    for (int sl = 0; sl < 8; ++sl) {
      const float* p = s2pp + (((size_t)bh * 4 + (sl >> 1)) * 2 + (sl & 1)) * 512 + base;
#pragma unroll
      for (int q = 0; q < 8; q += 4) {
        float4 v = *(const float4*)(p + q);
        vals[q + 0] = fmaxf(vals[q + 0], v.x);
        vals[q + 1] = fmaxf(vals[q + 1], v.y);
        vals[q + 2] = fmaxf(vals[q + 2], v.z);
        vals[q + 3] = fmaxf(vals[q + 3], v.w);
      }
    }
  }
#pragma unroll
  for (int q = 0; q < 8; ++q) vals[q] = tanhf(vals[q]);
  float mx = vals[0];
#pragma unroll
  for (int q = 1; q < 8; ++q) mx = fmaxf(mx, vals[q]);
#pragma unroll
  for (int off = 1; off < 64; off <<= 1) mx = fmaxf(mx, __shfl_xor(mx, off));
  float s = 0.0f;
#pragma unroll
  for (int q = 0; q < 8; ++q) {
    vals[q] = expf(vals[q] - mx);
    s += vals[q];
  }
#pragma unroll
  for (int off = 1; off < 64; off <<= 1) s += __shfl_xor(s, off);
  float inv = 1.0f / s;
#pragma unroll
  for (int q = 0; q < 8; ++q) vals[q] *= inv;

  int aoff = (side == 0 ? 16384 : 147456) + bh * 512 + base;
  *(float4*)(out + aoff) = make_float4(vals[0], vals[1], vals[2], vals[3]);
  *(float4*)(out + aoff + 4) = make_float4(vals[4], vals[5], vals[6], vals[7]);
  *(float4*)(&aL[h][base]) = make_float4(vals[0], vals[1], vals[2], vals[3]);
  *(float4*)(&aL[h][base + 4]) = make_float4(vals[4], vals[5], vals[6], vals[7]);
  __syncthreads();

  // readout: r[h][d] = sum_l aL[h][l] * X[l][b][d]
  const float4* X4 = (const float4*)(side == 0 ? X1 : X2);
  int q = t & 31, lg = t >> 5;
  f32x4 av[4];
  const f32x4 fz = {0.f, 0.f, 0.f, 0.f};
#pragma unroll
  for (int hh = 0; hh < 4; ++hh) av[hh] = fz;
#pragma unroll 4
  for (int l = lg; l < 512; l += 8) {
    float4 xv = X4[((size_t)l * Bn + b) * 32 + q];
#pragma unroll
    for (int hh = 0; hh < 4; ++hh) {
      float w = aL[hh][l];
      av[hh][0] += w * xv.x;
      av[hh][1] += w * xv.y;
      av[hh][2] += w * xv.z;
      av[hh][3] += w * xv.w;
    }
  }
#pragma unroll
  for (int hh = 0; hh < 4; ++hh) redv[hh][lg][q] = av[hh];
  __syncthreads();
  if (t < 128) {
    int d = t;
#pragma unroll
    for (int hh = 0; hh < 4; ++hh) {
      float s2 = 0.0f;
#pragma unroll
      for (int g = 0; g < 8; ++g) s2 += ((const float*)&redv[hh][g][d >> 2])[d & 3];
      rws[side * 32768 + (b * 4 + hh) * 128 + d] = s2;
    }
  }
}

// ---- k3: combine hops ----
__global__ __launch_bounds__(128) void k3(const float* __restrict__ rws,
                                          const float* __restrict__ Wipm,
                                          float* __restrict__ out) {
  int b = blockIdx.x, t = threadIdx.x;  // t = d
  __shared__ float r2l[4][128];
  __shared__ float tsum[2][4];
  float r1h[4], r2h[4];
#pragma unroll
  for (int h = 0; h < 4; ++h) {
    r1h[h] = rws[(b * 4 + h) * 128 + t];
    r2h[h] = rws[32768 + (b * 4 + h) * 128 + t];
    r2l[h][t] = r2h[h];
  }
  __syncthreads();
  float p[4] = {0, 0, 0, 0};
  for (int e = 0; e < 128; ++e) {
    float w = Wipm[t * 128 + e];
#pragma unroll
    for (int h = 0; h < 4; ++h) p[h] += w * r2l[h][e];
  }
#pragma unroll
  for (int h = 0; h < 4; ++h) p[h] *= r1h[h];
#pragma unroll
  for (int off = 1; off < 64; off <<= 1)
#pragma unroll
    for (int h = 0; h < 4; ++h) p[h] += __shfl_xor(p[h], off);
  if ((t & 63) == 0)
#pragma unroll
    for (int h = 0; h < 4; ++h) tsum[t >> 6][h] = p[h];
  __syncthreads();
  float ad[4], mx = -3.0e38f;
#pragma unroll
  for (int h = 0; h < 4; ++h) {
    float v = tanhf(tsum[0][h] + tsum[1][h]);
    ad[h] = v;
    mx = fmaxf(mx, v);
  }
  float s = 0.0f;
#pragma unroll
  for (int h = 0; h < 4; ++h) { ad[h] = expf(ad[h] - mx); s += ad[h]; }
  float inv = 1.0f / s;
#pragma unroll
  for (int h = 0; h < 4; ++h) ad[h] *= inv;
  if (t < 4) out[278528 + b * 4 + t] = ad[t];
  float f1 = 0.0f, f2 = 0.0f;
#pragma unroll
  for (int h = 0; h < 4; ++h) { f1 += ad[h] * r1h[h]; f2 += ad[h] * r2h[h]; }
  out[b * 128 + t] = f1;
  out[8192 + b * 128 + t] = f2;
}

extern "C" void kernel_launch(void* const* d_in, const int* in_sizes, int n_in,
                              void* d_out, int out_size, void* d_ws,
                              size_t ws_size, hipStream_t stream) {
  (void)in_sizes; (void)n_in; (void)out_size; (void)ws_size;
  const float* x1 = (const float*)d_in[0];
  const float* x2 = (const float*)d_in[1];
  const int* raw1 = (const int*)d_in[2];
  const int* raw2 = (const int*)d_in[3];
  const float* wu = (const float*)d_in[4];
  const float* wipm = (const float*)d_in[5];
  float* out = (float*)d_out;
  unsigned short* zimg = (unsigned short*)d_ws;      // 64 MiB
  float* s1pp = (float*)((char*)d_ws + 67108864);    // 1 MiB  [bh][lt][cb][128]
  float* s2pp = (float*)((char*)d_ws + 68157440);    // 4 MiB  [bh][lt][rg][512]
  float* rws = (float*)((char*)d_ws + 72351744);     // 256 KiB [side][bh][128]

  kz<<<1024, 256, 0, stream>>>(x2, wu, zimg);
  k1<<<1024, 256, 0, stream>>>(x1, zimg, raw1, raw2, s1pp, s2pp);
  k2<<<128, 256, 0, stream>>>(s1pp, s2pp, x1, x2, out, rws);
  k3<<<64, 128, 0, stream>>>(rws, wipm, out);
}